// Round 3
// baseline (766.204 us; speedup 1.0000x reference)
//
#include <hip/hip_runtime.h>
#include <cstdint>
#include <cstddef>

#define B_ 16
#define C_ 64
#define N_ 2048
#define K_ 20

// K1: replicate np.sum(xt*xt, axis=-1) in f32: elementwise rounded products,
// then numpy pairwise_sum for n=64: 8 accumulators + fixed combine tree.
__global__ __launch_bounds__(256) void k_sq(const float* __restrict__ x,
                                            float* __restrict__ sqf) {
    int i = blockIdx.x * 256 + threadIdx.x;   // 0..B_*N_-1
    int b = i >> 11, n = i & (N_ - 1);
    const float* xb = x + (size_t)b * C_ * N_ + n;
    float p[C_];
#pragma unroll
    for (int c = 0; c < C_; ++c) {
        float v = xb[(size_t)c * N_];
        p[c] = __fmul_rn(v, v);
    }
    float r[8];
#pragma unroll
    for (int k = 0; k < 8; ++k) r[k] = p[k];
#pragma unroll
    for (int ii = 8; ii < 64; ii += 8) {
#pragma unroll
        for (int k = 0; k < 8; ++k) r[k] = __fadd_rn(r[k], p[ii + k]);
    }
    float s0 = __fadd_rn(__fadd_rn(r[0], r[1]), __fadd_rn(r[2], r[3]));
    float s1 = __fadd_rn(__fadd_rn(r[4], r[5]), __fadd_rn(r[6], r[7]));
    sqf[i] = __fadd_rn(s0, s1);
}

// K3: Yt[b][m][o] = sum_c (W[o][c] - W[o][64+c]) * x[b][c][m]
__global__ __launch_bounds__(256) void k_y(const float* __restrict__ x,
                                           const float* __restrict__ W,
                                           float* __restrict__ Yt) {
    __shared__ float Al[C_ * 64];  // [c][o]
    __shared__ float xl[C_ * 64];  // [c][m]
    int tid = threadIdx.x;
    int bid = blockIdx.x;
    int b = bid >> 5;              // 32 m-tiles per batch
    int m0 = (bid & 31) * 64;
    {
        int o = tid & 63, cb = tid >> 6;
#pragma unroll
        for (int j = 0; j < 16; ++j) {
            int c = cb * 16 + j;
            Al[c * 64 + o] = W[o * 128 + c] - W[o * 128 + 64 + c];
            xl[c * 64 + o] = x[((size_t)b * C_ + c) * N_ + m0 + o];  // o used as m-lane
        }
    }
    __syncthreads();
    int ml = tid & 63, og = tid >> 6;  // og -> 16 consecutive o
    float acc[16];
#pragma unroll
    for (int j = 0; j < 16; ++j) acc[j] = 0.f;
#pragma unroll 4
    for (int c = 0; c < C_; ++c) {
        float xv = xl[c * 64 + ml];
        const float4* a4 = reinterpret_cast<const float4*>(&Al[c * 64 + og * 16]);
#pragma unroll
        for (int q = 0; q < 4; ++q) {
            float4 av = a4[q];
            acc[q * 4 + 0] = fmaf(av.x, xv, acc[q * 4 + 0]);
            acc[q * 4 + 1] = fmaf(av.y, xv, acc[q * 4 + 1]);
            acc[q * 4 + 2] = fmaf(av.z, xv, acc[q * 4 + 2]);
            acc[q * 4 + 3] = fmaf(av.w, xv, acc[q * 4 + 3]);
        }
    }
    float* yp = Yt + ((size_t)b * N_ + m0 + ml) * C_ + og * 16;
#pragma unroll
    for (int q = 0; q < 4; ++q) {
        reinterpret_cast<float4*>(yp)[q] =
            make_float4(acc[q * 4 + 0], acc[q * 4 + 1], acc[q * 4 + 2], acc[q * 4 + 3]);
    }
}

// K2: exact replication of the numpy f32 pipeline.
// dot: sequential c=0..63, separate mul/add roundings (NO fma).
// dist = (sq_n - 2*dot) + sq_m, f32-rounded per op.
// ranking: stable ascending by (dist, index) via u64 key = (mono32(dist)<<11)|m.
__global__ __launch_bounds__(256) void k_knn3(const float* __restrict__ x,
                                              const float* __restrict__ sqf,
                                              float* __restrict__ idxf) {
    __shared__ unsigned long long dl[N_];
    __shared__ unsigned long long wl[4];
    int tid = threadIdx.x;
    int bid = blockIdx.x;            // B_*N_ = 32768
    int b = bid >> 11, n = bid & (N_ - 1);
    const float* xb = x + (size_t)b * C_ * N_;

    float row[C_];
#pragma unroll
    for (int c = 0; c < C_; ++c) row[c] = xb[(size_t)c * N_ + n];
    float sqn = sqf[b * N_ + n];

    float acc[8];
#pragma unroll
    for (int t = 0; t < 8; ++t) acc[t] = 0.f;
    for (int c = 0; c < C_; ++c) {
        const float* xc = xb + (size_t)c * N_ + tid;
        float rc = row[c];
#pragma unroll
        for (int t = 0; t < 8; ++t)
            acc[t] = __fadd_rn(acc[t], __fmul_rn(rc, xc[t * 256]));
    }
#pragma unroll
    for (int t = 0; t < 8; ++t) {
        int m = tid + t * 256;
        float d = __fadd_rn(__fsub_rn(sqn, __fmul_rn(2.0f, acc[t])), sqf[b * N_ + m]);
        unsigned ub = __float_as_uint(d);
        unsigned key = (ub & 0x80000000u) ? ~ub : (ub | 0x80000000u);  // monotone map
        dl[m] = ((unsigned long long)key << 11) | (unsigned)m;
    }
    __syncthreads();

    int lane = tid & 63, w = tid >> 6;
    for (int r = 0; r < K_; ++r) {
        unsigned long long best = ~0ull;
        for (int m = tid; m < N_; m += 256) {
            unsigned long long v = dl[m];
            if (v < best) best = v;
        }
#pragma unroll
        for (int d2 = 1; d2 < 64; d2 <<= 1) {
            unsigned long long o =
                (unsigned long long)__shfl_xor((long long)best, d2, 64);
            if (o < best) best = o;
        }
        if (lane == 0) wl[w] = best;
        __syncthreads();
        if (tid == 0) {
            unsigned long long bb = wl[0];
#pragma unroll
            for (int w2 = 1; w2 < 4; ++w2)
                if (wl[w2] < bb) bb = wl[w2];
            int bi = (int)(bb & 2047ull);
            idxf[((size_t)b * N_ + n) * K_ + r] = (float)bi;
            dl[bi] = ~0ull;
        }
        __syncthreads();
    }
}

// K4: out[b][o][n] = leaky( s[o]*(u + max_k Yt[b][idx[n][k]][o]) + t[o] )
__global__ __launch_bounds__(256) void k_out(const float* __restrict__ x,
                                             const float* __restrict__ W,
                                             const float* __restrict__ gamma,
                                             const float* __restrict__ beta,
                                             const float* __restrict__ rmean,
                                             const float* __restrict__ rvar,
                                             const float* __restrict__ Yt,
                                             const float* __restrict__ idxf,
                                             float* __restrict__ out) {
    __shared__ float Bl[C_ * 64];    // [c][o] = W[o][64+c]
    __shared__ float xl[C_ * 64];    // [c][nl]
    __shared__ float resl[64 * 65];  // [o][nl], padded
    __shared__ float sl[64], tl[64];
    int tid = threadIdx.x;
    int bid = blockIdx.x;
    int b = bid >> 5;
    int n0 = (bid & 31) * 64;
    {
        int o = tid & 63, cb = tid >> 6;
#pragma unroll
        for (int j = 0; j < 16; ++j) {
            int c = cb * 16 + j;
            Bl[c * 64 + o] = W[o * 128 + 64 + c];
            xl[c * 64 + o] = x[((size_t)b * C_ + c) * N_ + n0 + o];  // o as n-lane
        }
        if (tid < 64) {
            float s = gamma[tid] / sqrtf(rvar[tid] + 1e-5f);
            sl[tid] = s;
            tl[tid] = beta[tid] - rmean[tid] * s;
        }
    }
    __syncthreads();
    int w = tid >> 6, o = tid & 63;
    for (int i = 0; i < 16; ++i) {
        int nl = w * 16 + i;
        int n = n0 + nl;
        float u = 0.f;
#pragma unroll 8
        for (int c = 0; c < C_; ++c)
            u = fmaf(Bl[c * 64 + o], xl[c * 64 + nl], u);
        const float* ip = idxf + ((size_t)b * N_ + n) * K_;
        float v = -3.4e38f;
#pragma unroll
        for (int k = 0; k < K_; ++k) {
            int mi = (int)ip[k];
            v = fmaxf(v, Yt[((size_t)b * N_ + mi) * C_ + o]);
        }
        float h = u + v;
        float val = sl[o] * h + tl[o];
        val = val > 0.f ? val : 0.2f * val;
        resl[o * 65 + nl] = val;
    }
    __syncthreads();
    {
        int nl = tid & 63, ob = tid >> 6;
#pragma unroll
        for (int j = 0; j < 16; ++j) {
            int o2 = ob * 16 + j;
            out[((size_t)b * C_ + o2) * N_ + n0 + nl] = resl[o2 * 65 + nl];
        }
    }
}

extern "C" void kernel_launch(void* const* d_in, const int* in_sizes, int n_in,
                              void* d_out, int out_size, void* d_ws, size_t ws_size,
                              hipStream_t stream) {
    const float* x     = (const float*)d_in[0];
    const float* W     = (const float*)d_in[1];
    const float* gamma = (const float*)d_in[2];
    const float* beta  = (const float*)d_in[3];
    const float* rmean = (const float*)d_in[4];
    const float* rvar  = (const float*)d_in[5];

    float* out  = (float*)d_out;                         // [16][64][2048]
    float* idxf = out + (size_t)B_ * C_ * N_;            // [16][2048][20] as floats

    char* ws   = (char*)d_ws;
    float* sqf = (float*)ws;                             // 128 KB
    float* Yt  = (float*)(ws + 131072);                  // 8 MB

    k_sq  <<<B_ * N_ / 256, 256, 0, stream>>>(x, sqf);
    k_y   <<<B_ * (N_ / 64), 256, 0, stream>>>(x, W, Yt);
    k_knn3<<<B_ * N_, 256, 0, stream>>>(x, sqf, idxf);
    k_out <<<B_ * (N_ / 64), 256, 0, stream>>>(x, W, gamma, beta, rmean, rvar, Yt, idxf, out);
}